// Round 1
// baseline (603.481 us; speedup 1.0000x reference)
//
#include <hip/hip_runtime.h>

typedef __bf16 bf16x8 __attribute__((ext_vector_type(8)));
typedef float f32x4 __attribute__((ext_vector_type(4)));

#define LSEQ 2048

__device__ __forceinline__ unsigned short f2b(float f){
  unsigned u = __builtin_bit_cast(unsigned, f);
  u += 0x7FFFu + ((u >> 16) & 1u);
  return (unsigned short)(u >> 16);
}
__device__ __forceinline__ float b2f(unsigned short h){
  unsigned u = ((unsigned)h) << 16;
  return __builtin_bit_cast(float, u);
}

// ---- X fp32 -> bf16, 4 elems/thread ----
__global__ __launch_bounds__(256) void cvt_f32_bf16(const float* __restrict__ in,
                                                    unsigned short* __restrict__ out){
  int tid = blockIdx.x * 256 + threadIdx.x;
  float4 v = reinterpret_cast<const float4*>(in)[tid];
  ushort4 o;
  o.x = f2b(v.x); o.y = f2b(v.y); o.z = f2b(v.z); o.w = f2b(v.w);
  reinterpret_cast<ushort4*>(out)[tid] = o;
}

// ---- transpose + convert: in fp32 [R][C] -> out bf16 [C][R] ----
__global__ __launch_bounds__(256) void transpose_cvt(const float* __restrict__ in,
                                                     unsigned short* __restrict__ out,
                                                     int R, int C){
  __shared__ float t[32][33];
  int c0 = blockIdx.x * 32, r0 = blockIdx.y * 32;
  int tx = threadIdx.x, ty = threadIdx.y;
  #pragma unroll
  for (int i = 0; i < 4; i++){
    int r = ty + i*8;
    t[r][tx] = in[(size_t)(r0 + r) * C + c0 + tx];
  }
  __syncthreads();
  #pragma unroll
  for (int i = 0; i < 4; i++){
    int c = ty + i*8;
    out[(size_t)(c0 + c) * R + r0 + tx] = f2b(t[tx][c]);
  }
}

// ---- RoPE trig tables: [L][64] ----
__global__ __launch_bounds__(256) void trig_init(float* __restrict__ cosT,
                                                 float* __restrict__ sinT){
  int tid = blockIdx.x * 256 + threadIdx.x; // l*64 + i
  int i = tid & 63; int l = tid >> 6;
  float invf = powf(10000.0f, -((float)(2*i)) / 128.0f);
  float ang = (float)l * invf;
  cosT[tid] = cosf(ang);
  sinT[tid] = sinf(ang);
}

// ---- RoPE on Q,K: qkv bf16 [4096][6144] -> Qr,Kr bf16 [32][2048][128] ----
// Q additionally scaled by log2(e)/sqrt(D) so softmax can use exp2.
__global__ __launch_bounds__(256) void rope_qk(const unsigned short* __restrict__ qkv,
                                               const float* __restrict__ cosT,
                                               const float* __restrict__ sinT,
                                               unsigned short* __restrict__ Qr,
                                               unsigned short* __restrict__ Kr){
  int tid = blockIdx.x * 256 + threadIdx.x; // B*H*L*64 = 4194304
  int i  = tid & 63;
  int l  = (tid >> 6) & (LSEQ - 1);
  int bh = tid >> 17;
  int b = bh >> 4, h = bh & 15;
  size_t base = (size_t)(b*LSEQ + l) * 6144 + h*384;
  float c = cosT[l*64 + i], s = sinT[l*64 + i];
  float q1 = b2f(qkv[base + 2*i]),       q2 = b2f(qkv[base + 2*i + 1]);
  float k1 = b2f(qkv[base + 128 + 2*i]), k2 = b2f(qkv[base + 128 + 2*i + 1]);
  const float qs = 0.12751691f; // log2(e)/sqrt(128)
  size_t ob = ((size_t)bh*LSEQ + l) * 128;
  Qr[ob + 2*i]     = f2b((q1*c - q2*s) * qs);
  Qr[ob + 2*i + 1] = f2b((q1*s + q2*c) * qs);
  Kr[ob + 2*i]     = f2b(k1*c - k2*s);
  Kr[ob + 2*i + 1] = f2b(k1*s + k2*c);
}

// ---- V transpose: qkv -> Vt bf16 [32][128][2048] ----
__global__ __launch_bounds__(256) void vtrans(const unsigned short* __restrict__ qkv,
                                              unsigned short* __restrict__ Vt){
  __shared__ unsigned short t[64][65];
  int d0 = blockIdx.x * 64, l0 = blockIdx.y * 64, bh = blockIdx.z;
  int b = bh >> 4, h = bh & 15;
  int tx = threadIdx.x, ty = threadIdx.y; // (64,4)
  #pragma unroll
  for (int i = 0; i < 16; i++){
    int lr = ty + i*4;
    t[lr][tx] = qkv[(size_t)(b*LSEQ + l0 + lr) * 6144 + h*384 + 256 + d0 + tx];
  }
  __syncthreads();
  #pragma unroll
  for (int i = 0; i < 16; i++){
    int dr = ty + i*4;
    Vt[(size_t)(bh*128 + d0 + dr) * LSEQ + l0 + tx] = t[tx][dr];
  }
}

// ---- GEMM: C[M][N] = A[M][K] * Bt[N][K]^T ; bf16 in, fp32 acc ----
// 128x128 tile, 4 waves (2x2 of 64x64), BK=64, XOR-swizzled LDS.
template<bool BF16_OUT>
__global__ __launch_bounds__(256) void gemm_bt(const unsigned short* __restrict__ A,
                                               const unsigned short* __restrict__ Bt,
                                               void* __restrict__ Cp,
                                               int M, int N, int K){
  __shared__ __align__(16) unsigned short As[128*64];
  __shared__ __align__(16) unsigned short Bs[128*64];
  int m0 = blockIdx.y * 128, n0 = blockIdx.x * 128;
  int tid = threadIdx.x, lane = tid & 63, wave = tid >> 6;
  int wm = wave >> 1, wn = wave & 1;
  int lr = lane & 15, lh = lane >> 4;
  f32x4 acc[4][4];
  #pragma unroll
  for (int a = 0; a < 4; a++)
    #pragma unroll
    for (int bb = 0; bb < 4; bb++)
      acc[a][bb] = (f32x4){0.f, 0.f, 0.f, 0.f};

  int nk = K >> 6;
  for (int k0 = 0; k0 < nk; k0++){
    __syncthreads();
    #pragma unroll
    for (int it = 0; it < 4; it++){
      int u = it*256 + tid;
      int r = u >> 3, c = u & 7;
      bf16x8 va = *reinterpret_cast<const bf16x8*>(A  + (size_t)(m0 + r)*K + k0*64 + c*8);
      *reinterpret_cast<bf16x8*>(&As[r*64 + ((c ^ (r & 7)) * 8)]) = va;
      bf16x8 vb = *reinterpret_cast<const bf16x8*>(Bt + (size_t)(n0 + r)*K + k0*64 + c*8);
      *reinterpret_cast<bf16x8*>(&Bs[r*64 + ((c ^ (r & 7)) * 8)]) = vb;
    }
    __syncthreads();
    #pragma unroll
    for (int kk = 0; kk < 2; kk++){
      bf16x8 af[4], bfg[4];
      #pragma unroll
      for (int f = 0; f < 4; f++){
        int ra = wm*64 + f*16 + lr;
        af[f]  = *reinterpret_cast<const bf16x8*>(&As[ra*64 + (((kk*4 + lh) ^ (ra & 7)) * 8)]);
        int rb = wn*64 + f*16 + lr;
        bfg[f] = *reinterpret_cast<const bf16x8*>(&Bs[rb*64 + (((kk*4 + lh) ^ (rb & 7)) * 8)]);
      }
      #pragma unroll
      for (int fm = 0; fm < 4; fm++)
        #pragma unroll
        for (int fn = 0; fn < 4; fn++)
          acc[fm][fn] = __builtin_amdgcn_mfma_f32_16x16x32_bf16(af[fm], bfg[fn], acc[fm][fn], 0, 0, 0);
    }
  }
  #pragma unroll
  for (int fm = 0; fm < 4; fm++)
    #pragma unroll
    for (int fn = 0; fn < 4; fn++)
      #pragma unroll
      for (int r = 0; r < 4; r++){
        int row = m0 + wm*64 + fm*16 + lh*4 + r;
        int col = n0 + wn*64 + fn*16 + lr;
        float v = acc[fm][fn][r];
        if (BF16_OUT) ((unsigned short*)Cp)[(size_t)row*N + col] = f2b(v);
        else          ((float*)Cp)[(size_t)row*N + col] = v;
      }
}

// ---- Flash attention: Qr,Kr [32][2048][128], Vt [32][128][2048] -> aout bf16 [B][L][H*D]
__global__ __launch_bounds__(256) void attn_kernel(const unsigned short* __restrict__ Qr,
                                                   const unsigned short* __restrict__ Kr,
                                                   const unsigned short* __restrict__ Vt,
                                                   unsigned short* __restrict__ aout){
  __shared__ __align__(16) unsigned short Ks[64*128];
  __shared__ __align__(16) unsigned short Vs[128*64];
  __shared__ __align__(16) unsigned short Ps[4][16*64];
  int bh = blockIdx.y;
  int q0 = (int)(gridDim.x - 1 - blockIdx.x) * 64; // longest blocks first
  int tid = threadIdx.x;
  int wave = tid >> 6, lane = tid & 63;
  int lr = lane & 15, lh = lane >> 4;

  // Q fragments in registers (16 rows x 128, per wave)
  bf16x8 qf[4];
  const unsigned short* Qbase = Qr + ((size_t)bh*LSEQ + q0 + wave*16 + lr) * 128;
  #pragma unroll
  for (int kc = 0; kc < 4; kc++)
    qf[kc] = *reinterpret_cast<const bf16x8*>(Qbase + kc*32 + lh*8);

  float m_i[4], l_i[4];
  f32x4 o[8];
  #pragma unroll
  for (int r = 0; r < 4; r++){ m_i[r] = -__builtin_inff(); l_i[r] = 0.f; }
  #pragma unroll
  for (int nd = 0; nd < 8; nd++) o[nd] = (f32x4){0.f, 0.f, 0.f, 0.f};

  int ntiles = (q0 >> 6) + 1;
  for (int t = 0; t < ntiles; t++){
    int kv0 = t * 64;
    __syncthreads();
    #pragma unroll
    for (int it = 0; it < 4; it++){
      int u = it*256 + tid;
      int rk = u >> 4, ck = u & 15;
      bf16x8 vk = *reinterpret_cast<const bf16x8*>(Kr + ((size_t)bh*LSEQ + kv0 + rk)*128 + ck*8);
      *reinterpret_cast<bf16x8*>(&Ks[rk*128 + ((ck ^ (rk & 7)) * 8)]) = vk;
      int rv = u >> 3, cv = u & 7;
      bf16x8 vv = *reinterpret_cast<const bf16x8*>(Vt + ((size_t)bh*128 + rv)*LSEQ + kv0 + cv*8);
      *reinterpret_cast<bf16x8*>(&Vs[rv*64 + ((cv ^ (rv & 7)) * 8)]) = vv;
    }
    __syncthreads();

    // S = Q @ K^T  (already in log2 units; scale folded into Q)
    f32x4 s[4];
    #pragma unroll
    for (int nc = 0; nc < 4; nc++){
      s[nc] = (f32x4){0.f, 0.f, 0.f, 0.f};
      #pragma unroll
      for (int kc = 0; kc < 4; kc++){
        int n = nc*16 + lr;
        bf16x8 kf = *reinterpret_cast<const bf16x8*>(&Ks[n*128 + (((kc*4 + lh) ^ (n & 7)) * 8)]);
        s[nc] = __builtin_amdgcn_mfma_f32_16x16x32_bf16(qf[kc], kf, s[nc], 0, 0, 0);
      }
    }
    if (t == ntiles - 1){ // diagonal tile: causal mask
      #pragma unroll
      for (int nc = 0; nc < 4; nc++)
        #pragma unroll
        for (int r = 0; r < 4; r++){
          int q  = q0 + wave*16 + lh*4 + r;
          int kv = kv0 + nc*16 + lr;
          if (kv > q) s[nc][r] = -__builtin_inff();
        }
    }
    // online softmax (rows m = lh*4+r; reduce across 16 lanes of same lh)
    float pm[4];
    #pragma unroll
    for (int r = 0; r < 4; r++)
      pm[r] = fmaxf(fmaxf(s[0][r], s[1][r]), fmaxf(s[2][r], s[3][r]));
    #pragma unroll
    for (int off = 1; off < 16; off <<= 1)
      #pragma unroll
      for (int r = 0; r < 4; r++)
        pm[r] = fmaxf(pm[r], __shfl_xor(pm[r], off, 64));
    float al[4], rs[4];
    #pragma unroll
    for (int r = 0; r < 4; r++){
      float mn = fmaxf(m_i[r], pm[r]);
      al[r] = exp2f(m_i[r] - mn);
      m_i[r] = mn;
      rs[r] = 0.f;
    }
    #pragma unroll
    for (int nc = 0; nc < 4; nc++)
      #pragma unroll
      for (int r = 0; r < 4; r++){
        float p = exp2f(s[nc][r] - m_i[r]);
        s[nc][r] = p;
        rs[r] += p;
      }
    #pragma unroll
    for (int off = 1; off < 16; off <<= 1)
      #pragma unroll
      for (int r = 0; r < 4; r++)
        rs[r] += __shfl_xor(rs[r], off, 64);
    #pragma unroll
    for (int r = 0; r < 4; r++)
      l_i[r] = l_i[r]*al[r] + rs[r];
    #pragma unroll
    for (int nd = 0; nd < 8; nd++)
      #pragma unroll
      for (int r = 0; r < 4; r++)
        o[nd][r] *= al[r];
    // P -> per-wave LDS (swizzled), then read back as A-fragments
    #pragma unroll
    for (int nc = 0; nc < 4; nc++)
      #pragma unroll
      for (int r = 0; r < 4; r++){
        int m = lh*4 + r;
        int col = nc*16 + lr;
        Ps[wave][m*64 + (((col >> 3) ^ (m & 7)) * 8) + (col & 7)] = f2b(s[nc][r]);
      }
    #pragma unroll
    for (int kc = 0; kc < 2; kc++){
      bf16x8 pa = *reinterpret_cast<const bf16x8*>(&Ps[wave][lr*64 + (((kc*4 + lh) ^ (lr & 7)) * 8)]);
      #pragma unroll
      for (int nd = 0; nd < 8; nd++){
        int d = nd*16 + lr;
        bf16x8 vf = *reinterpret_cast<const bf16x8*>(&Vs[d*64 + (((kc*4 + lh) ^ (d & 7)) * 8)]);
        o[nd] = __builtin_amdgcn_mfma_f32_16x16x32_bf16(pa, vf, o[nd], 0, 0, 0);
      }
    }
  }
  float inv[4];
  #pragma unroll
  for (int r = 0; r < 4; r++) inv[r] = 1.0f / l_i[r];
  int b = bh >> 4, h = bh & 15;
  #pragma unroll
  for (int nd = 0; nd < 8; nd++)
    #pragma unroll
    for (int r = 0; r < 4; r++){
      int q = q0 + wave*16 + lh*4 + r;
      aout[((size_t)b*LSEQ + q)*2048 + h*128 + nd*16 + lr] = f2b(o[nd][r] * inv[r]);
    }
}

extern "C" void kernel_launch(void* const* d_in, const int* in_sizes, int n_in,
                              void* d_out, int out_size, void* d_ws, size_t ws_size,
                              hipStream_t stream){
  const float* X  = (const float*)d_in[0];
  const float* Wq = (const float*)d_in[1];
  const float* Wo = (const float*)d_in[2];
  float* out = (float*)d_out;
  char* ws = (char*)d_ws;
  // workspace layout (bytes)
  unsigned short* Xb   = (unsigned short*)(ws + 0);          // 16 MB  (reused as Qr)
  unsigned short* Wt   = (unsigned short*)(ws + 16777216);   // 24 MB
  unsigned short* Wot  = (unsigned short*)(ws + 41943040);   // 8 MB
  unsigned short* QKV  = (unsigned short*)(ws + 50331648);   // 48 MB (reused as attn out)
  unsigned short* Kr   = (unsigned short*)(ws + 100663296);  // 16 MB
  unsigned short* Vt   = (unsigned short*)(ws + 117440512);  // 16 MB
  float* cosT          = (float*)(ws + 134217728);           // 512 KB
  float* sinT          = (float*)(ws + 134742016);           // 512 KB
  unsigned short* Qr   = Xb;
  unsigned short* Aout = QKV;

  cvt_f32_bf16<<<8192, 256, 0, stream>>>(X, Xb);
  transpose_cvt<<<dim3(192, 64), dim3(32, 8), 0, stream>>>(Wq, Wt, 2048, 6144);
  transpose_cvt<<<dim3(64, 64),  dim3(32, 8), 0, stream>>>(Wo, Wot, 2048, 2048);
  trig_init<<<512, 256, 0, stream>>>(cosT, sinT);
  gemm_bt<true><<<dim3(48, 32), 256, 0, stream>>>(Xb, Wt, (void*)QKV, 4096, 6144, 2048);
  rope_qk<<<16384, 256, 0, stream>>>(QKV, cosT, sinT, Qr, Kr);
  vtrans<<<dim3(2, 32, 32), dim3(64, 4), 0, stream>>>(QKV, Vt);
  attn_kernel<<<dim3(32, 32), 256, 0, stream>>>(Qr, Kr, Vt, Aout);
  gemm_bt<false><<<dim3(16, 32), 256, 0, stream>>>(Aout, Wot, (void*)out, 4096, 2048, 2048);
}

// Round 2
// 421.708 us; speedup vs baseline: 1.4310x; 1.4310x over previous
//
#include <hip/hip_runtime.h>

typedef __bf16 bf16x8 __attribute__((ext_vector_type(8)));
typedef float f32x4 __attribute__((ext_vector_type(4)));

#define LSEQ 2048

__device__ __forceinline__ unsigned short f2b(float f){
  unsigned u = __builtin_bit_cast(unsigned, f);
  u += 0x7FFFu + ((u >> 16) & 1u);
  return (unsigned short)(u >> 16);
}
__device__ __forceinline__ float b2f(unsigned short h){
  unsigned u = ((unsigned)h) << 16;
  return __builtin_bit_cast(float, u);
}

// async global->LDS, 16B per lane; LDS dest = wave-uniform base + lane*16
typedef __attribute__((address_space(1))) const unsigned int glb_u32;
typedef __attribute__((address_space(3))) unsigned int lds_u32;
__device__ __forceinline__ void gld_lds16(const void* g, void* l){
  __builtin_amdgcn_global_load_lds((glb_u32*)g, (lds_u32*)l, 16, 0, 0);
}

// ---- X fp32 -> bf16, 4 elems/thread ----
__global__ __launch_bounds__(256) void cvt_f32_bf16(const float* __restrict__ in,
                                                    unsigned short* __restrict__ out){
  int tid = blockIdx.x * 256 + threadIdx.x;
  float4 v = reinterpret_cast<const float4*>(in)[tid];
  ushort4 o;
  o.x = f2b(v.x); o.y = f2b(v.y); o.z = f2b(v.z); o.w = f2b(v.w);
  reinterpret_cast<ushort4*>(out)[tid] = o;
}

// ---- transpose + convert: in fp32 [R][C] -> out bf16 [C][R] ----
__global__ __launch_bounds__(256) void transpose_cvt(const float* __restrict__ in,
                                                     unsigned short* __restrict__ out,
                                                     int R, int C){
  __shared__ float t[32][33];
  int c0 = blockIdx.x * 32, r0 = blockIdx.y * 32;
  int tx = threadIdx.x, ty = threadIdx.y;
  #pragma unroll
  for (int i = 0; i < 4; i++){
    int r = ty + i*8;
    t[r][tx] = in[(size_t)(r0 + r) * C + c0 + tx];
  }
  __syncthreads();
  #pragma unroll
  for (int i = 0; i < 4; i++){
    int c = ty + i*8;
    out[(size_t)(c0 + c) * R + r0 + tx] = f2b(t[tx][c]);
  }
}

// ---- RoPE trig tables: [L][64] ----
__global__ __launch_bounds__(256) void trig_init(float* __restrict__ cosT,
                                                 float* __restrict__ sinT){
  int tid = blockIdx.x * 256 + threadIdx.x; // l*64 + i
  int i = tid & 63; int l = tid >> 6;
  float invf = powf(10000.0f, -((float)(2*i)) / 128.0f);
  float ang = (float)l * invf;
  cosT[tid] = cosf(ang);
  sinT[tid] = sinf(ang);
}

// ---- RoPE on Q,K: qkv bf16 [4096][6144] -> Qr,Kr bf16 [32][2048][128] ----
__global__ __launch_bounds__(256) void rope_qk(const unsigned short* __restrict__ qkv,
                                               const float* __restrict__ cosT,
                                               const float* __restrict__ sinT,
                                               unsigned short* __restrict__ Qr,
                                               unsigned short* __restrict__ Kr){
  int tid = blockIdx.x * 256 + threadIdx.x; // B*H*L*64 = 4194304
  int i  = tid & 63;
  int l  = (tid >> 6) & (LSEQ - 1);
  int bh = tid >> 17;
  int b = bh >> 4, h = bh & 15;
  size_t base = (size_t)(b*LSEQ + l) * 6144 + h*384;
  float c = cosT[l*64 + i], s = sinT[l*64 + i];
  float q1 = b2f(qkv[base + 2*i]),       q2 = b2f(qkv[base + 2*i + 1]);
  float k1 = b2f(qkv[base + 128 + 2*i]), k2 = b2f(qkv[base + 128 + 2*i + 1]);
  const float qs = 0.12751691f; // log2(e)/sqrt(128)
  size_t ob = ((size_t)bh*LSEQ + l) * 128;
  Qr[ob + 2*i]     = f2b((q1*c - q2*s) * qs);
  Qr[ob + 2*i + 1] = f2b((q1*s + q2*c) * qs);
  Kr[ob + 2*i]     = f2b(k1*c - k2*s);
  Kr[ob + 2*i + 1] = f2b(k1*s + k2*c);
}

// ---- V transpose: qkv -> Vt bf16 [32][128][2048] ----
__global__ __launch_bounds__(256) void vtrans(const unsigned short* __restrict__ qkv,
                                              unsigned short* __restrict__ Vt){
  __shared__ unsigned short t[64][65];
  int d0 = blockIdx.x * 64, l0 = blockIdx.y * 64, bh = blockIdx.z;
  int b = bh >> 4, h = bh & 15;
  int tx = threadIdx.x, ty = threadIdx.y; // (64,4)
  #pragma unroll
  for (int i = 0; i < 16; i++){
    int lr = ty + i*4;
    t[lr][tx] = qkv[(size_t)(b*LSEQ + l0 + lr) * 6144 + h*384 + 256 + d0 + tx];
  }
  __syncthreads();
  #pragma unroll
  for (int i = 0; i < 16; i++){
    int dr = ty + i*4;
    Vt[(size_t)(bh*128 + d0 + dr) * LSEQ + l0 + tx] = t[tx][dr];
  }
}

// ---- GEMM: C[M][N] = A[M][K] * Bt[N][K]^T ; bf16 in, fp32 acc ----
// 128x128 tile, 4 waves (2x2 of 64x64), BK=64, linear LDS via global_load_lds
// with pre-swizzled global source; reads XOR-swizzled (rule #21).
template<bool BF16_OUT>
__global__ __launch_bounds__(256) void gemm_bt(const unsigned short* __restrict__ A,
                                               const unsigned short* __restrict__ Bt,
                                               void* __restrict__ Cp,
                                               int M, int N, int K){
  __shared__ __align__(16) unsigned short As[128*64];
  __shared__ __align__(16) unsigned short Bs[128*64];
  int m0 = blockIdx.y * 128, n0 = blockIdx.x * 128;
  int tid = threadIdx.x, lane = tid & 63, wave = tid >> 6;
  int wm = wave >> 1, wn = wave & 1;
  int lr = lane & 15, lh = lane >> 4;
  int r8 = lane >> 3;               // row within 8-row chunk (also row&7)
  int cg = (lane & 7) ^ r8;         // pre-swizzled source col granule
  f32x4 acc[4][4];
  #pragma unroll
  for (int a = 0; a < 4; a++)
    #pragma unroll
    for (int bb = 0; bb < 4; bb++)
      acc[a][bb] = (f32x4){0.f, 0.f, 0.f, 0.f};

  const unsigned short* Abase = A  + (size_t)(m0 + wave*32 + r8)*K + cg*8;
  const unsigned short* Bbase = Bt + (size_t)(n0 + wave*32 + r8)*K + cg*8;

  int nk = K >> 6;
  for (int k0 = 0; k0 < nk; k0++){
    __syncthreads();
    #pragma unroll
    for (int i = 0; i < 4; i++){
      gld_lds16(Abase + (size_t)i*8*K + k0*64, &As[(wave*32 + i*8)*64]);
      gld_lds16(Bbase + (size_t)i*8*K + k0*64, &Bs[(wave*32 + i*8)*64]);
    }
    __syncthreads();
    #pragma unroll
    for (int kk = 0; kk < 2; kk++){
      bf16x8 af[4], bfg[4];
      #pragma unroll
      for (int f = 0; f < 4; f++){
        int ra = wm*64 + f*16 + lr;
        af[f]  = *reinterpret_cast<const bf16x8*>(&As[ra*64 + (((kk*4 + lh) ^ (ra & 7)) * 8)]);
        int rb = wn*64 + f*16 + lr;
        bfg[f] = *reinterpret_cast<const bf16x8*>(&Bs[rb*64 + (((kk*4 + lh) ^ (rb & 7)) * 8)]);
      }
      __builtin_amdgcn_s_setprio(1);
      #pragma unroll
      for (int fm = 0; fm < 4; fm++)
        #pragma unroll
        for (int fn = 0; fn < 4; fn++)
          acc[fm][fn] = __builtin_amdgcn_mfma_f32_16x16x32_bf16(af[fm], bfg[fn], acc[fm][fn], 0, 0, 0);
      __builtin_amdgcn_s_setprio(0);
    }
  }
  #pragma unroll
  for (int fm = 0; fm < 4; fm++)
    #pragma unroll
    for (int fn = 0; fn < 4; fn++)
      #pragma unroll
      for (int r = 0; r < 4; r++){
        int row = m0 + wm*64 + fm*16 + lh*4 + r;
        int col = n0 + wn*64 + fn*16 + lr;
        float v = acc[fm][fn][r];
        if (BF16_OUT) ((unsigned short*)Cp)[(size_t)row*N + col] = f2b(v);
        else          ((float*)Cp)[(size_t)row*N + col] = v;
      }
}

// ---- Flash attention: Q-block 128 (4 waves x 32 rows, 2 groups of 16),
// KV tile 64, double-buffered LDS staged by global_load_lds, 2-phase schedule.
__global__ __launch_bounds__(256) void attn_kernel(const unsigned short* __restrict__ Qr,
                                                   const unsigned short* __restrict__ Kr,
                                                   const unsigned short* __restrict__ Vt,
                                                   unsigned short* __restrict__ aout){
  __shared__ __align__(16) unsigned short Ks[2][64*128];
  __shared__ __align__(16) unsigned short Vs[2][128*64];
  __shared__ __align__(16) unsigned short Ps[4][2][16*64];
  int bh = blockIdx.x;                 // 32, fastest-varying => longest-first global order
  int q0 = (15 - (int)blockIdx.y) * 128;
  int tid = threadIdx.x;
  int wave = tid >> 6, lane = tid & 63;
  int lr = lane & 15, lh = lane >> 4;
  int b = bh >> 4, h = bh & 15;

  // Q fragments: 2 groups of 16 rows x 128
  bf16x8 qf[2][4];
  #pragma unroll
  for (int g = 0; g < 2; g++){
    const unsigned short* Qb = Qr + ((size_t)bh*LSEQ + q0 + wave*32 + g*16 + lr) * 128;
    #pragma unroll
    for (int kc = 0; kc < 4; kc++)
      qf[g][kc] = *reinterpret_cast<const bf16x8*>(Qb + kc*32 + lh*8);
  }

  float m_i[2][4], l_i[2][4];
  f32x4 o[2][8];
  #pragma unroll
  for (int g = 0; g < 2; g++)
    #pragma unroll
    for (int r = 0; r < 4; r++){ m_i[g][r] = -__builtin_inff(); l_i[g][r] = 0.f; }
  #pragma unroll
  for (int g = 0; g < 2; g++)
    #pragma unroll
    for (int nd = 0; nd < 8; nd++) o[g][nd] = (f32x4){0.f, 0.f, 0.f, 0.f};

  // staging lambda: K tile (64x128) rows w*16+i*4+(l>>4); V tile (128x64) rows w*32+i*8+(l>>3)
  const unsigned short* Kbh = Kr + (size_t)bh*LSEQ*128;
  const unsigned short* Vbh = Vt + (size_t)bh*128*LSEQ;
  int klrow = lane >> 4;   // 0..3
  int vlrow = lane >> 3;   // 0..7
  int vg = (lane & 7) ^ vlrow;

  int ntiles = (q0 >> 6) + 2;

  // prologue: stage tile 0 into buf 0
  {
    #pragma unroll
    for (int i = 0; i < 4; i++){
      int rk = wave*16 + i*4 + klrow;
      int gk = (lane & 15) ^ (rk & 7);
      gld_lds16(Kbh + (size_t)rk*128 + gk*8, &Ks[0][(wave*16 + i*4)*128]);
      int rv = wave*32 + i*8 + vlrow;
      gld_lds16(Vbh + (size_t)rv*LSEQ + vg*8, &Vs[0][(wave*32 + i*8)*64]);
    }
  }
  __syncthreads();

  int cur = 0;
  for (int t = 0; t < ntiles; t++){
    // issue next tile's loads early (overlap with compute below)
    if (t + 1 < ntiles){
      int kv1 = (t + 1) * 64;
      #pragma unroll
      for (int i = 0; i < 4; i++){
        int rk = wave*16 + i*4 + klrow;
        int gk = (lane & 15) ^ (rk & 7);
        gld_lds16(Kbh + (size_t)(kv1 + rk)*128 + gk*8, &Ks[cur^1][(wave*16 + i*4)*128]);
        int rv = wave*32 + i*8 + vlrow;
        gld_lds16(Vbh + (size_t)rv*LSEQ + kv1 + vg*8, &Vs[cur^1][(wave*32 + i*8)*64]);
      }
    }
    int kv0 = t * 64;

    // S = Q @ K^T (log2 units; scale folded into Q). K frags shared by both groups.
    f32x4 s[2][4];
    #pragma unroll
    for (int g = 0; g < 2; g++)
      #pragma unroll
      for (int nc = 0; nc < 4; nc++)
        s[g][nc] = (f32x4){0.f, 0.f, 0.f, 0.f};
    __builtin_amdgcn_s_setprio(1);
    #pragma unroll
    for (int nc = 0; nc < 4; nc++){
      int n = nc*16 + lr;
      #pragma unroll
      for (int kc = 0; kc < 4; kc++){
        bf16x8 kf = *reinterpret_cast<const bf16x8*>(&Ks[cur][n*128 + (((kc*4 + lh) ^ (n & 7)) * 8)]);
        s[0][nc] = __builtin_amdgcn_mfma_f32_16x16x32_bf16(qf[0][kc], kf, s[0][nc], 0, 0, 0);
        s[1][nc] = __builtin_amdgcn_mfma_f32_16x16x32_bf16(qf[1][kc], kf, s[1][nc], 0, 0, 0);
      }
    }
    __builtin_amdgcn_s_setprio(0);

    if (t >= ntiles - 2){ // diagonal tiles: causal mask
      #pragma unroll
      for (int g = 0; g < 2; g++)
        #pragma unroll
        for (int nc = 0; nc < 4; nc++)
          #pragma unroll
          for (int r = 0; r < 4; r++){
            int q  = q0 + wave*32 + g*16 + lh*4 + r;
            int kv = kv0 + nc*16 + lr;
            if (kv > q) s[g][nc][r] = -__builtin_inff();
          }
    }

    // online softmax per group (reduce across 16 lr-lanes)
    #pragma unroll
    for (int g = 0; g < 2; g++){
      float pm[4];
      #pragma unroll
      for (int r = 0; r < 4; r++)
        pm[r] = fmaxf(fmaxf(s[g][0][r], s[g][1][r]), fmaxf(s[g][2][r], s[g][3][r]));
      #pragma unroll
      for (int off = 1; off < 16; off <<= 1)
        #pragma unroll
        for (int r = 0; r < 4; r++)
          pm[r] = fmaxf(pm[r], __shfl_xor(pm[r], off, 64));
      float al[4], rs[4];
      #pragma unroll
      for (int r = 0; r < 4; r++){
        float mn = fmaxf(m_i[g][r], pm[r]);
        al[r] = exp2f(m_i[g][r] - mn);
        m_i[g][r] = mn;
        rs[r] = 0.f;
      }
      #pragma unroll
      for (int nc = 0; nc < 4; nc++)
        #pragma unroll
        for (int r = 0; r < 4; r++){
          float p = exp2f(s[g][nc][r] - m_i[g][r]);
          s[g][nc][r] = p;
          rs[r] += p;
        }
      #pragma unroll
      for (int off = 1; off < 16; off <<= 1)
        #pragma unroll
        for (int r = 0; r < 4; r++)
          rs[r] += __shfl_xor(rs[r], off, 64);
      #pragma unroll
      for (int r = 0; r < 4; r++)
        l_i[g][r] = l_i[g][r]*al[r] + rs[r];
      #pragma unroll
      for (int nd = 0; nd < 8; nd++)
        #pragma unroll
        for (int r = 0; r < 4; r++)
          o[g][nd][r] *= al[r];
      // P -> per-wave LDS (swizzled)
      #pragma unroll
      for (int nc = 0; nc < 4; nc++)
        #pragma unroll
        for (int r = 0; r < 4; r++){
          int m = lh*4 + r;
          int col = nc*16 + lr;
          Ps[wave][g][m*64 + (((col >> 3) ^ (m & 7)) * 8) + (col & 7)] = f2b(s[g][nc][r]);
        }
    }

    // PV: V frags shared by both groups
    __builtin_amdgcn_s_setprio(1);
    #pragma unroll
    for (int kc = 0; kc < 2; kc++){
      bf16x8 pa0 = *reinterpret_cast<const bf16x8*>(&Ps[wave][0][lr*64 + (((kc*4 + lh) ^ (lr & 7)) * 8)]);
      bf16x8 pa1 = *reinterpret_cast<const bf16x8*>(&Ps[wave][1][lr*64 + (((kc*4 + lh) ^ (lr & 7)) * 8)]);
      #pragma unroll
      for (int nd = 0; nd < 8; nd++){
        int d = nd*16 + lr;
        bf16x8 vf = *reinterpret_cast<const bf16x8*>(&Vs[cur][d*64 + (((kc*4 + lh) ^ (d & 7)) * 8)]);
        o[0][nd] = __builtin_amdgcn_mfma_f32_16x16x32_bf16(pa0, vf, o[0][nd], 0, 0, 0);
        o[1][nd] = __builtin_amdgcn_mfma_f32_16x16x32_bf16(pa1, vf, o[1][nd], 0, 0, 0);
      }
    }
    __builtin_amdgcn_s_setprio(0);

    __syncthreads(); // drains prefetch vmcnt + syncs buffers
    cur ^= 1;
  }

  #pragma unroll
  for (int g = 0; g < 2; g++){
    float inv[4];
    #pragma unroll
    for (int r = 0; r < 4; r++) inv[r] = 1.0f / l_i[g][r];
    #pragma unroll
    for (int nd = 0; nd < 8; nd++)
      #pragma unroll
      for (int r = 0; r < 4; r++){
        int q = q0 + wave*32 + g*16 + lh*4 + r;
        aout[((size_t)b*LSEQ + q)*2048 + h*128 + nd*16 + lr] = f2b(o[g][nd][r] * inv[r]);
      }
  }
}

extern "C" void kernel_launch(void* const* d_in, const int* in_sizes, int n_in,
                              void* d_out, int out_size, void* d_ws, size_t ws_size,
                              hipStream_t stream){
  const float* X  = (const float*)d_in[0];
  const float* Wq = (const float*)d_in[1];
  const float* Wo = (const float*)d_in[2];
  float* out = (float*)d_out;
  char* ws = (char*)d_ws;
  unsigned short* Xb   = (unsigned short*)(ws + 0);          // 16 MB  (reused as Qr)
  unsigned short* Wt   = (unsigned short*)(ws + 16777216);   // 24 MB
  unsigned short* Wot  = (unsigned short*)(ws + 41943040);   // 8 MB
  unsigned short* QKV  = (unsigned short*)(ws + 50331648);   // 48 MB (reused as attn out)
  unsigned short* Kr   = (unsigned short*)(ws + 100663296);  // 16 MB
  unsigned short* Vt   = (unsigned short*)(ws + 117440512);  // 16 MB
  float* cosT          = (float*)(ws + 134217728);           // 512 KB
  float* sinT          = (float*)(ws + 134742016);           // 512 KB
  unsigned short* Qr   = Xb;
  unsigned short* Aout = QKV;

  cvt_f32_bf16<<<8192, 256, 0, stream>>>(X, Xb);
  transpose_cvt<<<dim3(192, 64), dim3(32, 8), 0, stream>>>(Wq, Wt, 2048, 6144);
  transpose_cvt<<<dim3(64, 64),  dim3(32, 8), 0, stream>>>(Wo, Wot, 2048, 2048);
  trig_init<<<512, 256, 0, stream>>>(cosT, sinT);
  gemm_bt<true><<<dim3(48, 32), 256, 0, stream>>>(Xb, Wt, (void*)QKV, 4096, 6144, 2048);
  rope_qk<<<16384, 256, 0, stream>>>(QKV, cosT, sinT, Qr, Kr);
  vtrans<<<dim3(2, 32, 32), dim3(64, 4), 0, stream>>>(QKV, Vt);
  attn_kernel<<<dim3(32, 16), 256, 0, stream>>>(Qr, Kr, Vt, Aout);
  gemm_bt<false><<<dim3(16, 32), 256, 0, stream>>>(Aout, Wot, (void*)out, 4096, 2048, 2048);
}

// Round 3
// 420.577 us; speedup vs baseline: 1.4349x; 1.0027x over previous
//
#include <hip/hip_runtime.h>

typedef __bf16 bf16x8 __attribute__((ext_vector_type(8)));
typedef float f32x4 __attribute__((ext_vector_type(4)));

#define LSEQ 2048

__device__ __forceinline__ unsigned short f2b(float f){
  unsigned u = __builtin_bit_cast(unsigned, f);
  u += 0x7FFFu + ((u >> 16) & 1u);
  return (unsigned short)(u >> 16);
}
__device__ __forceinline__ float b2f(unsigned short h){
  unsigned u = ((unsigned)h) << 16;
  return __builtin_bit_cast(float, u);
}
__device__ __forceinline__ unsigned cvt_pk_bf16(float lo, float hi){
  unsigned r;
  asm("v_cvt_pk_bf16_f32 %0, %1, %2" : "=v"(r) : "v"(lo), "v"(hi));
  return r;
}

// async global->LDS, 16B per lane; LDS dest = wave-uniform base + lane*16
typedef __attribute__((address_space(1))) const unsigned int glb_u32;
typedef __attribute__((address_space(3))) unsigned int lds_u32;
__device__ __forceinline__ void gld_lds16(const void* g, void* l){
  __builtin_amdgcn_global_load_lds((glb_u32*)g, (lds_u32*)l, 16, 0, 0);
}

// ---- X fp32 -> bf16, 4 elems/thread ----
__global__ __launch_bounds__(256) void cvt_f32_bf16(const float* __restrict__ in,
                                                    unsigned short* __restrict__ out){
  int tid = blockIdx.x * 256 + threadIdx.x;
  float4 v = reinterpret_cast<const float4*>(in)[tid];
  ushort4 o;
  o.x = f2b(v.x); o.y = f2b(v.y); o.z = f2b(v.z); o.w = f2b(v.w);
  reinterpret_cast<ushort4*>(out)[tid] = o;
}

// ---- transpose + convert: in fp32 [R][C] -> out bf16 [C][R] ----
__global__ __launch_bounds__(256) void transpose_cvt(const float* __restrict__ in,
                                                     unsigned short* __restrict__ out,
                                                     int R, int C){
  __shared__ float t[32][33];
  int c0 = blockIdx.x * 32, r0 = blockIdx.y * 32;
  int tx = threadIdx.x, ty = threadIdx.y;
  #pragma unroll
  for (int i = 0; i < 4; i++){
    int r = ty + i*8;
    t[r][tx] = in[(size_t)(r0 + r) * C + c0 + tx];
  }
  __syncthreads();
  #pragma unroll
  for (int i = 0; i < 4; i++){
    int c = ty + i*8;
    out[(size_t)(c0 + c) * R + r0 + tx] = f2b(t[tx][c]);
  }
}

// ---- RoPE trig tables: [L][64] ----
__global__ __launch_bounds__(256) void trig_init(float* __restrict__ cosT,
                                                 float* __restrict__ sinT){
  int tid = blockIdx.x * 256 + threadIdx.x; // l*64 + i
  int i = tid & 63; int l = tid >> 6;
  float invf = powf(10000.0f, -((float)(2*i)) / 128.0f);
  float ang = (float)l * invf;
  cosT[tid] = cosf(ang);
  sinT[tid] = sinf(ang);
}

// ---- RoPE on Q,K: qkv bf16 [4096][6144] -> Qr,Kr bf16 [32][2048][128] ----
__global__ __launch_bounds__(256) void rope_qk(const unsigned short* __restrict__ qkv,
                                               const float* __restrict__ cosT,
                                               const float* __restrict__ sinT,
                                               unsigned short* __restrict__ Qr,
                                               unsigned short* __restrict__ Kr){
  int tid = blockIdx.x * 256 + threadIdx.x; // B*H*L*64 = 4194304
  int i  = tid & 63;
  int l  = (tid >> 6) & (LSEQ - 1);
  int bh = tid >> 17;
  int b = bh >> 4, h = bh & 15;
  size_t base = (size_t)(b*LSEQ + l) * 6144 + h*384;
  float c = cosT[l*64 + i], s = sinT[l*64 + i];
  float q1 = b2f(qkv[base + 2*i]),       q2 = b2f(qkv[base + 2*i + 1]);
  float k1 = b2f(qkv[base + 128 + 2*i]), k2 = b2f(qkv[base + 128 + 2*i + 1]);
  const float qs = 0.12751691f; // log2(e)/sqrt(128)
  size_t ob = ((size_t)bh*LSEQ + l) * 128;
  Qr[ob + 2*i]     = f2b((q1*c - q2*s) * qs);
  Qr[ob + 2*i + 1] = f2b((q1*s + q2*c) * qs);
  Kr[ob + 2*i]     = f2b(k1*c - k2*s);
  Kr[ob + 2*i + 1] = f2b(k1*s + k2*c);
}

// ---- V transpose: qkv -> Vt bf16 [32][128][2048] ----
__global__ __launch_bounds__(256) void vtrans(const unsigned short* __restrict__ qkv,
                                              unsigned short* __restrict__ Vt){
  __shared__ unsigned short t[64][65];
  int d0 = blockIdx.x * 64, l0 = blockIdx.y * 64, bh = blockIdx.z;
  int b = bh >> 4, h = bh & 15;
  int tx = threadIdx.x, ty = threadIdx.y; // (64,4)
  #pragma unroll
  for (int i = 0; i < 16; i++){
    int lr = ty + i*4;
    t[lr][tx] = qkv[(size_t)(b*LSEQ + l0 + lr) * 6144 + h*384 + 256 + d0 + tx];
  }
  __syncthreads();
  #pragma unroll
  for (int i = 0; i < 16; i++){
    int dr = ty + i*4;
    Vt[(size_t)(bh*128 + d0 + dr) * LSEQ + l0 + tx] = t[tx][dr];
  }
}

// ---- GEMM: C[M][N] = A[M][K] * Bt[N][K]^T ; bf16 in, fp32 acc ----
template<bool BF16_OUT>
__global__ __launch_bounds__(256) void gemm_bt(const unsigned short* __restrict__ A,
                                               const unsigned short* __restrict__ Bt,
                                               void* __restrict__ Cp,
                                               int M, int N, int K){
  __shared__ __align__(16) unsigned short As[128*64];
  __shared__ __align__(16) unsigned short Bs[128*64];
  int m0 = blockIdx.y * 128, n0 = blockIdx.x * 128;
  int tid = threadIdx.x, lane = tid & 63, wave = tid >> 6;
  int wm = wave >> 1, wn = wave & 1;
  int lr = lane & 15, lh = lane >> 4;
  int r8 = lane >> 3;
  int cg = (lane & 7) ^ r8;
  f32x4 acc[4][4];
  #pragma unroll
  for (int a = 0; a < 4; a++)
    #pragma unroll
    for (int bb = 0; bb < 4; bb++)
      acc[a][bb] = (f32x4){0.f, 0.f, 0.f, 0.f};

  const unsigned short* Abase = A  + (size_t)(m0 + wave*32 + r8)*K + cg*8;
  const unsigned short* Bbase = Bt + (size_t)(n0 + wave*32 + r8)*K + cg*8;

  int nk = K >> 6;
  for (int k0 = 0; k0 < nk; k0++){
    __syncthreads();
    #pragma unroll
    for (int i = 0; i < 4; i++){
      gld_lds16(Abase + (size_t)i*8*K + k0*64, &As[(wave*32 + i*8)*64]);
      gld_lds16(Bbase + (size_t)i*8*K + k0*64, &Bs[(wave*32 + i*8)*64]);
    }
    __syncthreads();
    #pragma unroll
    for (int kk = 0; kk < 2; kk++){
      bf16x8 af[4], bfg[4];
      #pragma unroll
      for (int f = 0; f < 4; f++){
        int ra = wm*64 + f*16 + lr;
        af[f]  = *reinterpret_cast<const bf16x8*>(&As[ra*64 + (((kk*4 + lh) ^ (ra & 7)) * 8)]);
        int rb = wn*64 + f*16 + lr;
        bfg[f] = *reinterpret_cast<const bf16x8*>(&Bs[rb*64 + (((kk*4 + lh) ^ (rb & 7)) * 8)]);
      }
      __builtin_amdgcn_s_setprio(1);
      #pragma unroll
      for (int fm = 0; fm < 4; fm++)
        #pragma unroll
        for (int fn = 0; fn < 4; fn++)
          acc[fm][fn] = __builtin_amdgcn_mfma_f32_16x16x32_bf16(af[fm], bfg[fn], acc[fm][fn], 0, 0, 0);
      __builtin_amdgcn_s_setprio(0);
    }
  }
  #pragma unroll
  for (int fm = 0; fm < 4; fm++)
    #pragma unroll
    for (int fn = 0; fn < 4; fn++)
      #pragma unroll
      for (int r = 0; r < 4; r++){
        int row = m0 + wm*64 + fm*16 + lh*4 + r;
        int col = n0 + wn*64 + fn*16 + lr;
        float v = acc[fm][fn][r];
        if (BF16_OUT) ((unsigned short*)Cp)[(size_t)row*N + col] = f2b(v);
        else          ((float*)Cp)[(size_t)row*N + col] = v;
      }
}

// ---- Flash attention, swapped-QK^T softmax (lane owns q = lane&15) ----
// Q-block 128 (4 waves x 32 rows = 2 groups of 16), KV tile 64, dbuf LDS.
__global__ __launch_bounds__(256) void attn_kernel(const unsigned short* __restrict__ Qr,
                                                   const unsigned short* __restrict__ Kr,
                                                   const unsigned short* __restrict__ Vt,
                                                   unsigned short* __restrict__ aout){
  __shared__ __align__(16) unsigned short Ks[2][64*128];
  __shared__ __align__(16) unsigned short Vs[2][128*64];
  __shared__ __align__(16) unsigned short Ps[4][2][16*64];
  int bh = blockIdx.x;                 // fastest-varying
  int y = blockIdx.y;
  int qi = (y < 8) ? (15 - y) : (y - 8);   // pairs (15,0),(14,1)... equal work per CU
  int q0 = qi * 128;
  int tid = threadIdx.x;
  int wave = tid >> 6, lane = tid & 63;
  int lr = lane & 15, lh = lane >> 4;
  int b = bh >> 4, h = bh & 15;

  bf16x8 qf[2][4];
  #pragma unroll
  for (int g = 0; g < 2; g++){
    const unsigned short* Qb = Qr + ((size_t)bh*LSEQ + q0 + wave*32 + g*16 + lr) * 128;
    #pragma unroll
    for (int kc = 0; kc < 4; kc++)
      qf[g][kc] = *reinterpret_cast<const bf16x8*>(Qb + kc*32 + lh*8);
  }

  float m_i[2], l_i[2];
  f32x4 o[2][8];
  #pragma unroll
  for (int g = 0; g < 2; g++){ m_i[g] = -__builtin_inff(); l_i[g] = 0.f; }
  #pragma unroll
  for (int g = 0; g < 2; g++)
    #pragma unroll
    for (int nd = 0; nd < 8; nd++) o[g][nd] = (f32x4){0.f, 0.f, 0.f, 0.f};

  const unsigned short* Kbh = Kr + (size_t)bh*LSEQ*128;
  const unsigned short* Vbh = Vt + (size_t)bh*128*LSEQ;
  int klrow = lane >> 4;
  int vlrow = lane >> 3;
  int vg = (lane & 7) ^ vlrow;
  int srcb = (lane & 48) + ((lane >> 2) & 12); // lane-base for row-form broadcast

  int ntiles = (q0 >> 6) + 2;

  // prologue: stage tile 0 into buf 0
  #pragma unroll
  for (int i = 0; i < 4; i++){
    int rk = wave*16 + i*4 + klrow;
    int gk = (lane & 15) ^ (rk & 7);
    gld_lds16(Kbh + (size_t)rk*128 + gk*8, &Ks[0][(wave*16 + i*4)*128]);
    int rv = wave*32 + i*8 + vlrow;
    gld_lds16(Vbh + (size_t)rv*LSEQ + vg*8, &Vs[0][(wave*32 + i*8)*64]);
  }
  __syncthreads();

  int cur = 0;
  for (int t = 0; t < ntiles; t++){
    if (t + 1 < ntiles){
      int kv1 = (t + 1) * 64;
      #pragma unroll
      for (int i = 0; i < 4; i++){
        int rk = wave*16 + i*4 + klrow;
        int gk = (lane & 15) ^ (rk & 7);
        gld_lds16(Kbh + (size_t)(kv1 + rk)*128 + gk*8, &Ks[cur^1][(wave*16 + i*4)*128]);
        int rv = wave*32 + i*8 + vlrow;
        gld_lds16(Vbh + (size_t)rv*LSEQ + kv1 + vg*8, &Vs[cur^1][(wave*32 + i*8)*64]);
      }
    }
    int kv0 = t * 64;

    // S^T = K @ Q^T : lane holds S[kv = nc*16+lh*4+r][q = lr] for each group
    f32x4 s[2][4];
    #pragma unroll
    for (int g = 0; g < 2; g++)
      #pragma unroll
      for (int nc = 0; nc < 4; nc++)
        s[g][nc] = (f32x4){0.f, 0.f, 0.f, 0.f};
    __builtin_amdgcn_s_setprio(1);
    #pragma unroll
    for (int nc = 0; nc < 4; nc++){
      int n = nc*16 + lr;
      #pragma unroll
      for (int kc = 0; kc < 4; kc++){
        bf16x8 kf = *reinterpret_cast<const bf16x8*>(&Ks[cur][n*128 + (((kc*4 + lh) ^ (n & 7)) * 8)]);
        s[0][nc] = __builtin_amdgcn_mfma_f32_16x16x32_bf16(kf, qf[0][kc], s[0][nc], 0, 0, 0);
        s[1][nc] = __builtin_amdgcn_mfma_f32_16x16x32_bf16(kf, qf[1][kc], s[1][nc], 0, 0, 0);
      }
    }
    __builtin_amdgcn_s_setprio(0);

    if (t >= ntiles - 2){ // diagonal tiles: causal mask (kv > q)
      #pragma unroll
      for (int g = 0; g < 2; g++)
        #pragma unroll
        for (int nc = 0; nc < 4; nc++)
          #pragma unroll
          for (int r = 0; r < 4; r++){
            int kv = kv0 + nc*16 + lh*4 + r;
            int q  = q0 + wave*32 + g*16 + lr;
            if (kv > q) s[g][nc][r] = -__builtin_inff();
          }
    }

    // online softmax: per-lane scalar state (q = lr), 2 shfl per reduce
    #pragma unroll
    for (int g = 0; g < 2; g++){
      float pm = -__builtin_inff();
      #pragma unroll
      for (int nc = 0; nc < 4; nc++)
        pm = fmaxf(pm, fmaxf(fmaxf(s[g][nc][0], s[g][nc][1]), fmaxf(s[g][nc][2], s[g][nc][3])));
      pm = fmaxf(pm, __shfl_xor(pm, 16, 64));
      pm = fmaxf(pm, __shfl_xor(pm, 32, 64));
      float mn = fmaxf(m_i[g], pm);
      float al = exp2f(m_i[g] - mn);
      m_i[g] = mn;
      float rs = 0.f;
      unsigned w[8];
      #pragma unroll
      for (int nc = 0; nc < 4; nc++){
        float p0 = exp2f(s[g][nc][0] - mn), p1 = exp2f(s[g][nc][1] - mn);
        float p2 = exp2f(s[g][nc][2] - mn), p3 = exp2f(s[g][nc][3] - mn);
        rs += (p0 + p1) + (p2 + p3);
        w[nc*2]     = cvt_pk_bf16(p0, p1);
        w[nc*2 + 1] = cvt_pk_bf16(p2, p3);
      }
      rs += __shfl_xor(rs, 16, 64);
      rs += __shfl_xor(rs, 32, 64);
      l_i[g] = l_i[g]*al + rs;
      // broadcast al to o-row form (row r needs al of q-lane lh*4+r)
      float al_r[4];
      #pragma unroll
      for (int r = 0; r < 4; r++) al_r[r] = __shfl(al, srcb + r, 64);
      #pragma unroll
      for (int nd = 0; nd < 8; nd++)
        #pragma unroll
        for (int r = 0; r < 4; r++)
          o[g][nd][r] *= al_r[r];
      // P (q=lr row, kv pairs in-lane) -> LDS, 8 x b32, 16B-granule swizzle
      #pragma unroll
      for (int nc = 0; nc < 4; nc++)
        #pragma unroll
        for (int hh = 0; hh < 2; hh++){
          int kvg = nc*2 + (lh >> 1);
          int klo = (lh & 1)*4 + 2*hh;
          *reinterpret_cast<unsigned*>(&Ps[wave][g][lr*64 + ((kvg ^ (lr & 7)) << 3) + klo]) = w[nc*2 + hh];
        }
    }

    // PV
    __builtin_amdgcn_s_setprio(1);
    #pragma unroll
    for (int kc = 0; kc < 2; kc++){
      bf16x8 pa0 = *reinterpret_cast<const bf16x8*>(&Ps[wave][0][lr*64 + (((kc*4 + lh) ^ (lr & 7)) << 3)]);
      bf16x8 pa1 = *reinterpret_cast<const bf16x8*>(&Ps[wave][1][lr*64 + (((kc*4 + lh) ^ (lr & 7)) << 3)]);
      #pragma unroll
      for (int nd = 0; nd < 8; nd++){
        int d = nd*16 + lr;
        bf16x8 vf = *reinterpret_cast<const bf16x8*>(&Vs[cur][d*64 + (((kc*4 + lh) ^ (d & 7)) << 3)]);
        o[0][nd] = __builtin_amdgcn_mfma_f32_16x16x32_bf16(pa0, vf, o[0][nd], 0, 0, 0);
        o[1][nd] = __builtin_amdgcn_mfma_f32_16x16x32_bf16(pa1, vf, o[1][nd], 0, 0, 0);
      }
    }
    __builtin_amdgcn_s_setprio(0);

    __syncthreads(); // drains prefetch vmcnt + buffer swap
    cur ^= 1;
  }

  #pragma unroll
  for (int g = 0; g < 2; g++){
    float inv = 1.0f / l_i[g];
    float inv_r[4];
    #pragma unroll
    for (int r = 0; r < 4; r++) inv_r[r] = __shfl(inv, srcb + r, 64);
    #pragma unroll
    for (int nd = 0; nd < 8; nd++)
      #pragma unroll
      for (int r = 0; r < 4; r++){
        int q = q0 + wave*32 + g*16 + lh*4 + r;
        aout[((size_t)b*LSEQ + q)*2048 + h*128 + nd*16 + lr] = f2b(o[g][nd][r] * inv_r[r]);
      }
  }
}

extern "C" void kernel_launch(void* const* d_in, const int* in_sizes, int n_in,
                              void* d_out, int out_size, void* d_ws, size_t ws_size,
                              hipStream_t stream){
  const float* X  = (const float*)d_in[0];
  const float* Wq = (const float*)d_in[1];
  const float* Wo = (const float*)d_in[2];
  float* out = (float*)d_out;
  char* ws = (char*)d_ws;
  unsigned short* Xb   = (unsigned short*)(ws + 0);          // 16 MB  (reused as Qr)
  unsigned short* Wt   = (unsigned short*)(ws + 16777216);   // 24 MB
  unsigned short* Wot  = (unsigned short*)(ws + 41943040);   // 8 MB
  unsigned short* QKV  = (unsigned short*)(ws + 50331648);   // 48 MB (reused as attn out)
  unsigned short* Kr   = (unsigned short*)(ws + 100663296);  // 16 MB
  unsigned short* Vt   = (unsigned short*)(ws + 117440512);  // 16 MB
  float* cosT          = (float*)(ws + 134217728);           // 512 KB
  float* sinT          = (float*)(ws + 134742016);           // 512 KB
  unsigned short* Qr   = Xb;
  unsigned short* Aout = QKV;

  cvt_f32_bf16<<<8192, 256, 0, stream>>>(X, Xb);
  transpose_cvt<<<dim3(192, 64), dim3(32, 8), 0, stream>>>(Wq, Wt, 2048, 6144);
  transpose_cvt<<<dim3(64, 64),  dim3(32, 8), 0, stream>>>(Wo, Wot, 2048, 2048);
  trig_init<<<512, 256, 0, stream>>>(cosT, sinT);
  gemm_bt<true><<<dim3(48, 32), 256, 0, stream>>>(Xb, Wt, (void*)QKV, 4096, 6144, 2048);
  rope_qk<<<16384, 256, 0, stream>>>(QKV, cosT, sinT, Qr, Kr);
  vtrans<<<dim3(2, 32, 32), dim3(64, 4), 0, stream>>>(QKV, Vt);
  attn_kernel<<<dim3(32, 16), 256, 0, stream>>>(Qr, Kr, Vt, Aout);
  gemm_bt<false><<<dim3(16, 32), 256, 0, stream>>>(Aout, Wot, (void*)out, 4096, 2048, 2048);
}

// Round 4
// 380.774 us; speedup vs baseline: 1.5849x; 1.1045x over previous
//
#include <hip/hip_runtime.h>

typedef __bf16 bf16x8 __attribute__((ext_vector_type(8)));
typedef float f32x4 __attribute__((ext_vector_type(4)));
typedef float f32x16 __attribute__((ext_vector_type(16)));
typedef unsigned u32x4 __attribute__((ext_vector_type(4)));

#define LSEQ 2048

__device__ __forceinline__ unsigned short f2b(float f){
  unsigned u = __builtin_bit_cast(unsigned, f);
  u += 0x7FFFu + ((u >> 16) & 1u);
  return (unsigned short)(u >> 16);
}
__device__ __forceinline__ float b2f(unsigned short h){
  unsigned u = ((unsigned)h) << 16;
  return __builtin_bit_cast(float, u);
}
__device__ __forceinline__ unsigned cvt_pk_bf16(float lo, float hi){
  unsigned r;
  asm("v_cvt_pk_bf16_f32 %0, %1, %2" : "=v"(r) : "v"(lo), "v"(hi));
  return r;
}

// async global->LDS, 16B per lane; LDS dest = wave-uniform base + lane*16
typedef __attribute__((address_space(1))) const unsigned int glb_u32;
typedef __attribute__((address_space(3))) unsigned int lds_u32;
__device__ __forceinline__ void gld_lds16(const void* g, void* l){
  __builtin_amdgcn_global_load_lds((glb_u32*)g, (lds_u32*)l, 16, 0, 0);
}

// ---- X fp32 -> bf16, 4 elems/thread ----
__global__ __launch_bounds__(256) void cvt_f32_bf16(const float* __restrict__ in,
                                                    unsigned short* __restrict__ out){
  int tid = blockIdx.x * 256 + threadIdx.x;
  float4 v = reinterpret_cast<const float4*>(in)[tid];
  ushort4 o;
  o.x = f2b(v.x); o.y = f2b(v.y); o.z = f2b(v.z); o.w = f2b(v.w);
  reinterpret_cast<ushort4*>(out)[tid] = o;
}

// ---- transpose + convert: in fp32 [R][C] -> out bf16 [C][R] ----
__global__ __launch_bounds__(256) void transpose_cvt(const float* __restrict__ in,
                                                     unsigned short* __restrict__ out,
                                                     int R, int C){
  __shared__ float t[32][33];
  int c0 = blockIdx.x * 32, r0 = blockIdx.y * 32;
  int tx = threadIdx.x, ty = threadIdx.y;
  #pragma unroll
  for (int i = 0; i < 4; i++){
    int r = ty + i*8;
    t[r][tx] = in[(size_t)(r0 + r) * C + c0 + tx];
  }
  __syncthreads();
  #pragma unroll
  for (int i = 0; i < 4; i++){
    int c = ty + i*8;
    out[(size_t)(c0 + c) * R + r0 + tx] = f2b(t[tx][c]);
  }
}

// ---- RoPE trig tables: [L][64] ----
__global__ __launch_bounds__(256) void trig_init(float* __restrict__ cosT,
                                                 float* __restrict__ sinT){
  int tid = blockIdx.x * 256 + threadIdx.x; // l*64 + i
  int i = tid & 63; int l = tid >> 6;
  float invf = powf(10000.0f, -((float)(2*i)) / 128.0f);
  float ang = (float)l * invf;
  cosT[tid] = cosf(ang);
  sinT[tid] = sinf(ang);
}

// ---- RoPE on Q,K: qkv bf16 [4096][6144] -> Qr,Kr bf16 [32][2048][128] ----
__global__ __launch_bounds__(256) void rope_qk(const unsigned short* __restrict__ qkv,
                                               const float* __restrict__ cosT,
                                               const float* __restrict__ sinT,
                                               unsigned short* __restrict__ Qr,
                                               unsigned short* __restrict__ Kr){
  int tid = blockIdx.x * 256 + threadIdx.x; // B*H*L*64 = 4194304
  int i  = tid & 63;
  int l  = (tid >> 6) & (LSEQ - 1);
  int bh = tid >> 17;
  int b = bh >> 4, h = bh & 15;
  size_t base = (size_t)(b*LSEQ + l) * 6144 + h*384;
  float c = cosT[l*64 + i], s = sinT[l*64 + i];
  float q1 = b2f(qkv[base + 2*i]),       q2 = b2f(qkv[base + 2*i + 1]);
  float k1 = b2f(qkv[base + 128 + 2*i]), k2 = b2f(qkv[base + 128 + 2*i + 1]);
  const float qs = 0.12751691f; // log2(e)/sqrt(128)
  size_t ob = ((size_t)bh*LSEQ + l) * 128;
  Qr[ob + 2*i]     = f2b((q1*c - q2*s) * qs);
  Qr[ob + 2*i + 1] = f2b((q1*s + q2*c) * qs);
  Kr[ob + 2*i]     = f2b(k1*c - k2*s);
  Kr[ob + 2*i + 1] = f2b(k1*s + k2*c);
}

// ---- V transpose: qkv -> Vt bf16 [32][128][2048] ----
__global__ __launch_bounds__(256) void vtrans(const unsigned short* __restrict__ qkv,
                                              unsigned short* __restrict__ Vt){
  __shared__ unsigned short t[64][65];
  int d0 = blockIdx.x * 64, l0 = blockIdx.y * 64, bh = blockIdx.z;
  int b = bh >> 4, h = bh & 15;
  int tx = threadIdx.x, ty = threadIdx.y; // (64,4)
  #pragma unroll
  for (int i = 0; i < 16; i++){
    int lr = ty + i*4;
    t[lr][tx] = qkv[(size_t)(b*LSEQ + l0 + lr) * 6144 + h*384 + 256 + d0 + tx];
  }
  __syncthreads();
  #pragma unroll
  for (int i = 0; i < 16; i++){
    int dr = ty + i*4;
    Vt[(size_t)(bh*128 + d0 + dr) * LSEQ + l0 + tx] = t[tx][dr];
  }
}

// ---- GEMM: C[M][N] = A[M][K] * Bt[N][K]^T ; bf16 in, fp32 acc ----
template<bool BF16_OUT>
__global__ __launch_bounds__(256) void gemm_bt(const unsigned short* __restrict__ A,
                                               const unsigned short* __restrict__ Bt,
                                               void* __restrict__ Cp,
                                               int M, int N, int K){
  __shared__ __align__(16) unsigned short As[128*64];
  __shared__ __align__(16) unsigned short Bs[128*64];
  int m0 = blockIdx.y * 128, n0 = blockIdx.x * 128;
  int tid = threadIdx.x, lane = tid & 63, wave = tid >> 6;
  int wm = wave >> 1, wn = wave & 1;
  int lr = lane & 15, lh = lane >> 4;
  int r8 = lane >> 3;
  int cg = (lane & 7) ^ r8;
  f32x4 acc[4][4];
  #pragma unroll
  for (int a = 0; a < 4; a++)
    #pragma unroll
    for (int bb = 0; bb < 4; bb++)
      acc[a][bb] = (f32x4){0.f, 0.f, 0.f, 0.f};

  const unsigned short* Abase = A  + (size_t)(m0 + wave*32 + r8)*K + cg*8;
  const unsigned short* Bbase = Bt + (size_t)(n0 + wave*32 + r8)*K + cg*8;

  int nk = K >> 6;
  for (int k0 = 0; k0 < nk; k0++){
    __syncthreads();
    #pragma unroll
    for (int i = 0; i < 4; i++){
      gld_lds16(Abase + (size_t)i*8*K + k0*64, &As[(wave*32 + i*8)*64]);
      gld_lds16(Bbase + (size_t)i*8*K + k0*64, &Bs[(wave*32 + i*8)*64]);
    }
    __syncthreads();
    #pragma unroll
    for (int kk = 0; kk < 2; kk++){
      bf16x8 af[4], bfg[4];
      #pragma unroll
      for (int f = 0; f < 4; f++){
        int ra = wm*64 + f*16 + lr;
        af[f]  = *reinterpret_cast<const bf16x8*>(&As[ra*64 + (((kk*4 + lh) ^ (ra & 7)) * 8)]);
        int rb = wn*64 + f*16 + lr;
        bfg[f] = *reinterpret_cast<const bf16x8*>(&Bs[rb*64 + (((kk*4 + lh) ^ (rb & 7)) * 8)]);
      }
      __builtin_amdgcn_s_setprio(1);
      #pragma unroll
      for (int fm = 0; fm < 4; fm++)
        #pragma unroll
        for (int fn = 0; fn < 4; fn++)
          acc[fm][fn] = __builtin_amdgcn_mfma_f32_16x16x32_bf16(af[fm], bfg[fn], acc[fm][fn], 0, 0, 0);
      __builtin_amdgcn_s_setprio(0);
    }
  }
  #pragma unroll
  for (int fm = 0; fm < 4; fm++)
    #pragma unroll
    for (int fn = 0; fn < 4; fn++)
      #pragma unroll
      for (int r = 0; r < 4; r++){
        int row = m0 + wm*64 + fm*16 + lh*4 + r;
        int col = n0 + wn*64 + fn*16 + lr;
        float v = acc[fm][fn][r];
        if (BF16_OUT) ((unsigned short*)Cp)[(size_t)row*N + col] = f2b(v);
        else          ((float*)Cp)[(size_t)row*N + col] = v;
      }
}

// ---- Flash attention, 32x32 MFMA, in-register softmax (m214 structure) ----
// 4 waves x QBLK=32 rows, KV tile 64, K/V dbuf LDS, defer-max THR=8 (log2).
__global__ __launch_bounds__(256, 2) void attn_kernel(const unsigned short* __restrict__ Qr,
                                                      const unsigned short* __restrict__ Kr,
                                                      const unsigned short* __restrict__ Vt,
                                                      unsigned short* __restrict__ aout){
  __shared__ __align__(16) unsigned short Ks[2][64*128];
  __shared__ __align__(16) unsigned short Vs[2][128*64];
  int bh = blockIdx.x;                 // fastest-varying
  int y = blockIdx.y;
  int qi = (y < 8) ? (15 - y) : (y - 8);   // pair long+short blocks per CU
  int q0 = qi * 128;
  int tid = threadIdx.x;
  int wave = tid >> 6, lane = tid & 63;
  int ql = lane & 31;          // q-row within warp's 32
  int hi = lane >> 5;
  int b = bh >> 4, h = bh & 15;

  // Q frags: Q[q0+wave*32+ql][ks*16 + hi*8 + 0..7], ks=0..7
  bf16x8 qf[8];
  const unsigned short* Qb = Qr + ((size_t)bh*LSEQ + q0 + wave*32 + ql) * 128 + hi*8;
  #pragma unroll
  for (int ks = 0; ks < 8; ks++)
    qf[ks] = *reinterpret_cast<const bf16x8*>(Qb + ks*16);

  float m_i = -1.0e38f, l_i = 0.f;
  f32x16 o[4];
  #pragma unroll
  for (int nd = 0; nd < 4; nd++) o[nd] = (f32x16)(0.f);

  const unsigned short* Kbh = Kr + (size_t)bh*LSEQ*128;
  const unsigned short* Vbh = Vt + (size_t)bh*128*LSEQ;
  int klrow = lane >> 4;   // 0..3
  int vlrow = lane >> 3;   // 0..7
  int vg = (lane & 7) ^ vlrow;

  int ntiles = (q0 >> 6) + 2;

  // prologue: stage tile 0 into buf 0
  #pragma unroll
  for (int i = 0; i < 4; i++){
    int rk = wave*16 + i*4 + klrow;
    int gk = (lane & 15) ^ (rk & 7);
    gld_lds16(Kbh + (size_t)rk*128 + gk*8, &Ks[0][(wave*16 + i*4)*128]);
    int rv = wave*32 + i*8 + vlrow;
    gld_lds16(Vbh + (size_t)rv*LSEQ + vg*8, &Vs[0][(wave*32 + i*8)*64]);
  }
  __syncthreads();

  int cur = 0;
  for (int t = 0; t < ntiles; t++){
    if (t + 1 < ntiles){
      int kv1 = (t + 1) * 64;
      #pragma unroll
      for (int i = 0; i < 4; i++){
        int rk = wave*16 + i*4 + klrow;
        int gk = (lane & 15) ^ (rk & 7);
        gld_lds16(Kbh + (size_t)(kv1 + rk)*128 + gk*8, &Ks[cur^1][(wave*16 + i*4)*128]);
        int rv = wave*32 + i*8 + vlrow;
        gld_lds16(Vbh + (size_t)rv*LSEQ + kv1 + vg*8, &Vs[cur^1][(wave*32 + i*8)*64]);
      }
    }
    int kv0 = t * 64;

    // S^T = K @ Q^T: sAcc[h2] holds S[kv=32h2+(r&3)+8(r>>2)+4hi][q=ql]
    f32x16 sa0 = (f32x16)(0.f), sa1 = (f32x16)(0.f);
    __builtin_amdgcn_s_setprio(1);
    #pragma unroll
    for (int ks = 0; ks < 8; ks++){
      int g = 2*ks + hi;   // d granule
      bf16x8 kf0 = *reinterpret_cast<const bf16x8*>(&Ks[cur][ql*128 + ((g ^ (ql & 7)) * 8)]);
      bf16x8 kf1 = *reinterpret_cast<const bf16x8*>(&Ks[cur][(32 + ql)*128 + ((g ^ ((32 + ql) & 7)) * 8)]);
      sa0 = __builtin_amdgcn_mfma_f32_32x32x16_bf16(kf0, qf[ks], sa0, 0, 0, 0);
      sa1 = __builtin_amdgcn_mfma_f32_32x32x16_bf16(kf1, qf[ks], sa1, 0, 0, 0);
    }
    __builtin_amdgcn_s_setprio(0);

    if (t >= ntiles - 2){ // diagonal tiles: causal mask (kv > q)
      int q = q0 + wave*32 + ql;
      #pragma unroll
      for (int r = 0; r < 16; r++){
        int kvb = kv0 + (r & 3) + 8*(r >> 2) + 4*hi;
        if (kvb > q)      sa0[r] = -1.0e38f;
        if (kvb + 32 > q) sa1[r] = -1.0e38f;
      }
    }

    // row max (q = ql; lane pair l, l^32 share row)
    float pm = -1.0e38f;
    #pragma unroll
    for (int r = 0; r < 16; r++) pm = fmaxf(pm, fmaxf(sa0[r], sa1[r]));
    pm = fmaxf(pm, __shfl_xor(pm, 32, 64));

    if (__any(pm > m_i + 8.0f)){  // defer-max: rescale only when needed
      float mn = fmaxf(m_i, pm);
      float al = exp2f(m_i - mn);
      m_i = mn;
      l_i *= al;
      #pragma unroll
      for (int r = 0; r < 16; r++){
        int qsrc = (r & 3) + 8*(r >> 2) + 4*hi;
        float alr = __shfl(al, qsrc, 64);
        o[0][r] *= alr; o[1][r] *= alr; o[2][r] *= alr; o[3][r] *= alr;
      }
    }

    // P = exp2(S - m); pack to bf16 words; row-sum
    float ps = 0.f;
    unsigned wlo[2][4], whi[2][4];
    #pragma unroll
    for (int a = 0; a < 4; a++){
      float p0 = exp2f(sa0[4*a]     - m_i);
      float p1 = exp2f(sa0[4*a + 1] - m_i);
      float p2 = exp2f(sa0[4*a + 2] - m_i);
      float p3 = exp2f(sa0[4*a + 3] - m_i);
      ps += (p0 + p1) + (p2 + p3);
      wlo[0][a] = cvt_pk_bf16(p0, p1);
      whi[0][a] = cvt_pk_bf16(p2, p3);
      float p4 = exp2f(sa1[4*a]     - m_i);
      float p5 = exp2f(sa1[4*a + 1] - m_i);
      float p6 = exp2f(sa1[4*a + 2] - m_i);
      float p7 = exp2f(sa1[4*a + 3] - m_i);
      ps += (p4 + p5) + (p6 + p7);
      wlo[1][a] = cvt_pk_bf16(p4, p5);
      whi[1][a] = cvt_pk_bf16(p6, p7);
    }
    ps += __shfl_xor(ps, 32, 64);
    l_i += ps;

    // exchange lane<->lane^32 halves to build PV A-frags pa[ks]:
    // pa[ks] covers kv = ks*16 + hi*8 + 0..7
    bf16x8 pa[4];
    #pragma unroll
    for (int h2 = 0; h2 < 2; h2++)
      #pragma unroll
      for (int a0 = 0; a0 < 4; a0 += 2){
        unsigned x  = wlo[h2][a0], y  = wlo[h2][a0 + 1];
        asm("v_permlane32_swap_b32 %0, %1" : "+v"(x), "+v"(y));
        unsigned x2 = whi[h2][a0], y2 = whi[h2][a0 + 1];
        asm("v_permlane32_swap_b32 %0, %1" : "+v"(x2), "+v"(y2));
        u32x4 w4 = (u32x4){x, x2, y, y2};
        pa[2*h2 + (a0 >> 1)] = __builtin_bit_cast(bf16x8, w4);
      }

    // PV: o[nd] += P[q][kv16] @ V[kv16][d32]
    __builtin_amdgcn_s_setprio(1);
    #pragma unroll
    for (int ks = 0; ks < 4; ks++){
      int g = 2*ks + hi;   // kv granule
      #pragma unroll
      for (int nd = 0; nd < 4; nd++){
        int dr = nd*32 + ql;
        bf16x8 vf = *reinterpret_cast<const bf16x8*>(&Vs[cur][dr*64 + ((g ^ (dr & 7)) * 8)]);
        o[nd] = __builtin_amdgcn_mfma_f32_32x32x16_bf16(pa[ks], vf, o[nd], 0, 0, 0);
      }
    }
    __builtin_amdgcn_s_setprio(0);

    __syncthreads(); // drains prefetch vmcnt + buffer swap
    cur ^= 1;
  }

  // epilogue: O[q=(r&3)+8(r>>2)+4hi][d=nd*32+ql], normalize by 1/l of that q
  float inv = 1.0f / l_i;
  #pragma unroll
  for (int r = 0; r < 16; r++){
    int qsrc = (r & 3) + 8*(r >> 2) + 4*hi;
    float invr = __shfl(inv, qsrc, 64);
    int q = q0 + wave*32 + qsrc;
    size_t rowb = ((size_t)b*LSEQ + q)*2048 + h*128 + ql;
    aout[rowb]      = f2b(o[0][r] * invr);
    aout[rowb + 32] = f2b(o[1][r] * invr);
    aout[rowb + 64] = f2b(o[2][r] * invr);
    aout[rowb + 96] = f2b(o[3][r] * invr);
  }
}

extern "C" void kernel_launch(void* const* d_in, const int* in_sizes, int n_in,
                              void* d_out, int out_size, void* d_ws, size_t ws_size,
                              hipStream_t stream){
  const float* X  = (const float*)d_in[0];
  const float* Wq = (const float*)d_in[1];
  const float* Wo = (const float*)d_in[2];
  float* out = (float*)d_out;
  char* ws = (char*)d_ws;
  unsigned short* Xb   = (unsigned short*)(ws + 0);          // 16 MB  (reused as Qr)
  unsigned short* Wt   = (unsigned short*)(ws + 16777216);   // 24 MB
  unsigned short* Wot  = (unsigned short*)(ws + 41943040);   // 8 MB
  unsigned short* QKV  = (unsigned short*)(ws + 50331648);   // 48 MB (reused as attn out)
  unsigned short* Kr   = (unsigned short*)(ws + 100663296);  // 16 MB
  unsigned short* Vt   = (unsigned short*)(ws + 117440512);  // 16 MB
  float* cosT          = (float*)(ws + 134217728);           // 512 KB
  float* sinT          = (float*)(ws + 134742016);           // 512 KB
  unsigned short* Qr   = Xb;
  unsigned short* Aout = QKV;

  cvt_f32_bf16<<<8192, 256, 0, stream>>>(X, Xb);
  transpose_cvt<<<dim3(192, 64), dim3(32, 8), 0, stream>>>(Wq, Wt, 2048, 6144);
  transpose_cvt<<<dim3(64, 64),  dim3(32, 8), 0, stream>>>(Wo, Wot, 2048, 2048);
  trig_init<<<512, 256, 0, stream>>>(cosT, sinT);
  gemm_bt<true><<<dim3(48, 32), 256, 0, stream>>>(Xb, Wt, (void*)QKV, 4096, 6144, 2048);
  rope_qk<<<16384, 256, 0, stream>>>(QKV, cosT, sinT, Qr, Kr);
  vtrans<<<dim3(2, 32, 32), dim3(64, 4), 0, stream>>>(QKV, Vt);
  attn_kernel<<<dim3(32, 16), 256, 0, stream>>>(Qr, Kr, Vt, Aout);
  gemm_bt<false><<<dim3(16, 32), 256, 0, stream>>>(Aout, Wot, (void*)out, 4096, 2048, 2048);
}